// Round 5
// baseline (2145.481 us; speedup 1.0000x reference)
//
#include <hip/hip_runtime.h>

// SimpleRNN (relu) scan: B=512, T=512, D=64, H=512, O=1.
// R5: single-WG-per-group, ZERO cross-WG exchange (R2-R4 postmortem: the
// agent-scope fence/L3 round trip per step was the invariant ~5k-cyc bottleneck,
// WRITE_SIZE 263MB = hbuf->HBM writeback).
// Weights (576 KB bf16) split across one CU's storage tiers per wave:
//   f = kc*8 + p (kc 0..17, p 0..7; wave owns cols (w*8+p)*16 + c):
//   f <  64 -> AGPR  (256 AGPRs, "+a" pinned)
//   f <  98 -> VGPR  (136 regs, "+v" pinned)
//   f < 133 -> LDS   (35 frags * 1KB per wave = 140 KB)
//   f < 144 -> L2-streamed each step (11 KB/wave, hidden under MFMA)
// h lives in LDS A-frag order (16 KB); x enters as per-lane register A-frags.
// 4 waves / 256 thr, 1 wave/SIMD (waves_per_eu(1,1)) -> 512-reg unified budget.

#define T_STEPS 512
#define D_IN    64
#define ROWS    16
#define THREADS 256

#define F_AGPR 64
#define F_VGPR 98
#define F_LDS  133
#define N_VGF  (F_VGPR - F_AGPR)   // 34
#define N_LDSF (F_LDS - F_VGPR)    // 35
#define N_STRM (144 - F_LDS)       // 11

#define WT_BYTES  (512*576*2)      // 589824

typedef float  floatx4 __attribute__((ext_vector_type(4)));
typedef __bf16 bf16x8  __attribute__((ext_vector_type(8)));

#define KEEPA(v) asm volatile("" : "+a"(v))
#define KEEPV(v) asm volatile("" : "+v"(v))

__device__ __forceinline__ unsigned short f2b(float f) {
    union { float f; unsigned int u; } v; v.f = f;
    unsigned int u = v.u;
    return (unsigned short)((u + 0x7FFFu + ((u >> 16) & 1u)) >> 16);  // RNE
}

// WT element f = ((ng*18 + kc)*64 + lane)*8 + j  encodes B[k][n]:
//   n = ng*16 + (lane&15),  k = kc*32 + (lane>>4)*8 + j
__global__ void prep_kernel(const float* __restrict__ Wx, const float* __restrict__ Wh,
                            unsigned short* __restrict__ WT) {
    int f = blockIdx.x * 256 + threadIdx.x;
    if (f >= 512 * 576) return;
    int j    = f & 7;
    int lane = (f >> 3) & 63;
    int blk  = f >> 9;
    int kc   = blk % 18;
    int ng   = blk / 18;
    int n = ng * 16 + (lane & 15);
    int k = kc * 32 + (lane >> 4) * 8 + j;
    float val = (k < 64) ? Wx[k * 512 + n] : Wh[(k - 64) * 512 + n];
    WT[f] = f2b(val);
}

__device__ __forceinline__ bf16x8 cvt8(floatx4 a, floatx4 b) {
    bf16x8 r;
    r[0] = (__bf16)a[0]; r[1] = (__bf16)a[1]; r[2] = (__bf16)a[2]; r[3] = (__bf16)a[3];
    r[4] = (__bf16)b[0]; r[5] = (__bf16)b[1]; r[6] = (__bf16)b[2]; r[7] = (__bf16)b[3];
    return r;
}

// weight fragment selector -- f must be a compile-time constant after unroll
#define WV(f) ( (f) < F_AGPR ? __builtin_bit_cast(bf16x8, agf[(f) < F_AGPR ? (f) : 0]) \
              : (f) < F_VGPR ? __builtin_bit_cast(bf16x8, vgf[((f) >= F_AGPR && (f) < F_VGPR) ? (f) - F_AGPR : 0]) \
              : (f) < F_LDS  ? *(const bf16x8*)(wLane + (((f) >= F_VGPR && (f) < F_LDS) ? (f) - F_VGPR : 0) * 1024) \
              : __builtin_bit_cast(bf16x8, sfr[((f) >= F_LDS) ? (f) - F_LDS : 0]) )

#define MFMA_KC(kc)                                                                   \
    {                                                                                 \
        bf16x8 aR = *(const bf16x8*)(aLane + ((kc) - 2) * 1024);                      \
        _Pragma("unroll")                                                             \
        for (int p = 0; p < 8; ++p)                                                   \
            acc[p] = __builtin_amdgcn_mfma_f32_16x16x32_bf16(aR, WV((kc) * 8 + p),    \
                                                             acc[p], 0, 0, 0);        \
    }

__global__ __launch_bounds__(THREADS, 1) __attribute__((amdgpu_waves_per_eu(1, 1)))
void rnn_scan_kernel(const float* __restrict__ x, const unsigned short* __restrict__ WT,
                     const float* __restrict__ b_rnn, const float* __restrict__ Wd,
                     const float* __restrict__ bd, float* __restrict__ out) {
    extern __shared__ char smem[];
    unsigned short* afrag = (unsigned short*)smem;   // 16 KB: h_{t} in A-frag order
    char* wlds = smem + 16384;                       // 4 waves * 35 frags * 1 KB

    const int tid  = threadIdx.x;
    const int lane = tid & 63;
    const int w    = tid >> 6;       // wave 0..3, owns ntiles w*8 .. w*8+7
    const int c    = lane & 15;
    const int quad = lane >> 4;
    const int r0   = blockIdx.x * ROWS;

    // ---- weights -> AGPR/VGPR ----
    floatx4 agf[F_AGPR];
    floatx4 vgf[N_VGF];
#pragma unroll
    for (int f = 0; f < F_AGPR; ++f) {
        const int kc = f >> 3, p = f & 7, ng = w * 8 + p;
        agf[f] = *(const floatx4*)(WT + (((size_t)ng * 18 + kc) * 64 + lane) * 8);
    }
#pragma unroll
    for (int f = F_AGPR; f < F_VGPR; ++f) {
        const int kc = f >> 3, p = f & 7, ng = w * 8 + p;
        vgf[f - F_AGPR] = *(const floatx4*)(WT + (((size_t)ng * 18 + kc) * 64 + lane) * 8);
    }
#pragma unroll
    for (int f = 0; f < F_AGPR; ++f) KEEPA(agf[f]);
#pragma unroll
    for (int f = 0; f < N_VGF; ++f) KEEPV(vgf[f]);

    // ---- weights -> LDS (wave-private region, conflict-free b128 layout) ----
#pragma unroll
    for (int l = 0; l < N_LDSF; ++l) {
        const int f = F_VGPR + l, kc = f >> 3, p = f & 7, ng = w * 8 + p;
        *(uint4*)(wlds + ((w * N_LDSF + l) << 10) + lane * 16) =
            *(const uint4*)(WT + (((size_t)ng * 18 + kc) * 64 + lane) * 8);
    }

    // stream vaddr per p: byte offset of frag (kc=16, ng=w*8+p), +1024 for kc=17
    unsigned svoff[8];
#pragma unroll
    for (int p = 0; p < 8; ++p)
        svoff[p] = (unsigned)((((w * 8 + p) * 18 + 16) << 10) + lane * 16);

    float bias[8];
#pragma unroll
    for (int p = 0; p < 8; ++p) bias[p] = b_rnn[(w * 8 + p) * 16 + c];

    // h-write byte offsets (A-frag position of own columns, r=0; +16B per r)
    int hoff[8];
#pragma unroll
    for (int p = 0; p < 8; ++p) {
        const int col = (w * 8 + p) * 16 + c;
        hoff[p] = (((col >> 5) * 64 + ((col >> 3) & 3) * 16 + quad * 4) * 8 + (col & 7)) * 2;
    }

    // zero h
    for (int i = tid; i < 1024; i += THREADS)
        ((uint4*)afrag)[i] = make_uint4(0, 0, 0, 0);
    __syncthreads();

    const char* aLane = (const char*)afrag + lane * 16;
    const char* wLane = wlds + (w * N_LDSF) * 1024 + lane * 16;
    const char* wtB   = (const char*)WT;
    // per-lane x source: row r0+c, element quad*8
    const float* xrow = x + ((size_t)(r0 + c) * T_STEPS) * D_IN + quad * 8;

#pragma unroll 1
    for (int t = 0; t < T_STEPS; ++t) {
        // x_t register loads (consumed at the tail -> latency hidden)
        const float* xp = xrow + (size_t)t * D_IN;
        floatx4 xa = *(const floatx4*)(xp);
        floatx4 xb = *(const floatx4*)(xp + 4);
        floatx4 xc = *(const floatx4*)(xp + 32);
        floatx4 xd = *(const floatx4*)(xp + 36);

        floatx4 sfr[N_STRM];
        // stream group 1: f = 133..137 (kc16 p5..7, kc17 p0..1)
#pragma unroll
        for (int i = 0; i < 5; ++i) {
            const int f = F_LDS + i, kc = f >> 3, p = f & 7;
            sfr[i] = *(const floatx4*)(wtB + svoff[p] + (kc == 17 ? 1024 : 0));
        }

        floatx4 acc[8];
#pragma unroll
        for (int p = 0; p < 8; ++p)
            acc[p] = (floatx4){bias[p], bias[p], bias[p], bias[p]};

        // h-part K chunks, first half
        MFMA_KC(2)  MFMA_KC(3)  MFMA_KC(4)  MFMA_KC(5)  MFMA_KC(6)
        MFMA_KC(7)  MFMA_KC(8)  MFMA_KC(9)  MFMA_KC(10)

        // stream group 2: f = 138..143 (kc17 p2..7)
#pragma unroll
        for (int i = 5; i < N_STRM; ++i) {
            const int f = F_LDS + i, kc = f >> 3, p = f & 7;
            sfr[i] = *(const floatx4*)(wtB + svoff[p] + (kc == 17 ? 1024 : 0));
        }

        MFMA_KC(11) MFMA_KC(12) MFMA_KC(13) MFMA_KC(14) MFMA_KC(15)
        MFMA_KC(16) MFMA_KC(17)

        // x-part (kc 0,1): A from registers
        {
            bf16x8 a0 = cvt8(xa, xb);
            bf16x8 a1 = cvt8(xc, xd);
#pragma unroll
            for (int p = 0; p < 8; ++p)
                acc[p] = __builtin_amdgcn_mfma_f32_16x16x32_bf16(a0, WV(p), acc[p], 0, 0, 0);
#pragma unroll
            for (int p = 0; p < 8; ++p)
                acc[p] = __builtin_amdgcn_mfma_f32_16x16x32_bf16(a1, WV(8 + p), acc[p], 0, 0, 0);
        }

        __syncthreads();   // all waves done reading h_{t-1} from afrag

        // epilogue: relu + pack h_t (bias already in acc init)
#pragma unroll
        for (int p = 0; p < 8; ++p) {
#pragma unroll
            for (int r = 0; r < 4; ++r) {
                float v = acc[p][r];
                v = v > 0.f ? v : 0.f;
                *(unsigned short*)((char*)afrag + hoff[p] + r * 16) =
                    __builtin_bit_cast(unsigned short, (__bf16)v);
            }
        }
        __syncthreads();
    }

    // ---- output head: out[b] = relu(h_511[b,:] . Wd + bd) ----
    {
        const int m  = tid >> 4;     // batch row 0..15
        const int cs = tid & 15;     // 32-col chunk
        float sum = 0.f;
#pragma unroll
        for (int q2 = 0; q2 < 4; ++q2) {
            const bf16x8 hv = *(const bf16x8*)(&afrag[cs * 512 + (q2 * 16 + m) * 8]);
#pragma unroll
            for (int j = 0; j < 8; ++j)
                sum += (float)hv[j] * Wd[cs * 32 + q2 * 8 + j];
        }
#pragma unroll
        for (int off = 1; off < 16; off <<= 1) sum += __shfl_xor(sum, off, 64);
        if (cs == 0) {
            float v = sum + bd[0];
            out[r0 + m] = v > 0.f ? v : 0.f;
        }
    }
}

extern "C" void kernel_launch(void* const* d_in, const int* in_sizes, int n_in,
                              void* d_out, int out_size, void* d_ws, size_t ws_size,
                              hipStream_t stream) {
    const float* x    = (const float*)d_in[0];
    const float* Wx   = (const float*)d_in[1];
    const float* Wh   = (const float*)d_in[2];
    const float* brnn = (const float*)d_in[3];
    const float* Wd   = (const float*)d_in[4];
    const float* bd   = (const float*)d_in[5];
    float* out = (float*)d_out;

    unsigned short* WT = (unsigned short*)d_ws;   // 589824 B

    prep_kernel<<<(512 * 576 + 255) / 256, 256, 0, stream>>>(Wx, Wh, WT);

    const int smem_bytes = 16384 + 4 * N_LDSF * 1024;   // 159744 <= 163840
    hipFuncSetAttribute((const void*)rnn_scan_kernel,
                        hipFuncAttributeMaxDynamicSharedMemorySize, smem_bytes);
    rnn_scan_kernel<<<32, THREADS, smem_bytes, stream>>>(x, WT, brnn, Wd, bd, out);
}

// Round 6
// 1955.066 us; speedup vs baseline: 1.0974x; 1.0974x over previous
//
#include <hip/hip_runtime.h>

// SimpleRNN (relu) scan: B=512, T=512, D=64, H=512, O=1.
// R6: single-WG-per-group (zero exchange, validated R5: WRITE_SIZE 263MB->0.9MB)
// + pipe-balanced weight tiers and real register headroom (R5 failed on latency
// serialization: 0 free VGPRs => 51 serialized ds_reads => 9840 cyc/step).
// Per wave (owns cols w*128..w*128+127, frag(kc,p), ng=w*8+p):
//   kc 2..9            -> AGPR  (64 frags, 256 AGPRs, "+a" pinned)
//   kc 10,11,12(p<4)   -> VGPR  (20 frags, 80 regs, "+v" pinned)
//   kc 12(p>=4)..16(p<6)-> LDS  (34 frags * 1KB per wave = 136 KB)
//   kc 16(p>=6),17,0,1 -> L2-streamed per step (26 KB/wave), 3 groups, issued early
// LDS/L1 balance: (16+34)*4KB/120B/cyc ~= (26*4+4)KB/64B/cyc ~= 1670 cyc, parallel pipes.
// A-frags (h) staged via two 8-deep register batches. 4 waves, 1/SIMD.

#define T_STEPS 512
#define D_IN    64
#define ROWS    16
#define THREADS 256
#define N_LDSF  34

typedef float  floatx4 __attribute__((ext_vector_type(4)));
typedef __bf16 bf16x8  __attribute__((ext_vector_type(8)));

#define KEEPA(v) asm volatile("" : "+a"(v))
#define KEEPV(v) asm volatile("" : "+v"(v))
#define BC8(v)   __builtin_bit_cast(bf16x8, v)

__device__ __forceinline__ unsigned short f2b(float f) {
    union { float f; unsigned int u; } v; v.f = f;
    unsigned int u = v.u;
    return (unsigned short)((u + 0x7FFFu + ((u >> 16) & 1u)) >> 16);  // RNE
}

// WT element f = ((ng*18 + kc)*64 + lane)*8 + j  encodes B[k][n]:
//   n = ng*16 + (lane&15),  k = kc*32 + (lane>>4)*8 + j
__global__ void prep_kernel(const float* __restrict__ Wx, const float* __restrict__ Wh,
                            unsigned short* __restrict__ WT) {
    int f = blockIdx.x * 256 + threadIdx.x;
    if (f >= 512 * 576) return;
    int j    = f & 7;
    int lane = (f >> 3) & 63;
    int blk  = f >> 9;
    int kc   = blk % 18;
    int ng   = blk / 18;
    int n = ng * 16 + (lane & 15);
    int k = kc * 32 + (lane >> 4) * 8 + j;
    float val = (k < 64) ? Wx[k * 512 + n] : Wh[(k - 64) * 512 + n];
    WT[f] = f2b(val);
}

__device__ __forceinline__ bf16x8 cvt8(floatx4 a, floatx4 b) {
    bf16x8 r;
    r[0] = (__bf16)a[0]; r[1] = (__bf16)a[1]; r[2] = (__bf16)a[2]; r[3] = (__bf16)a[3];
    r[4] = (__bf16)b[0]; r[5] = (__bf16)b[1]; r[6] = (__bf16)b[2]; r[7] = (__bf16)b[3];
    return r;
}

__global__ __launch_bounds__(THREADS, 1) __attribute__((amdgpu_waves_per_eu(1, 1)))
void rnn_scan_kernel(const float* __restrict__ x, const unsigned short* __restrict__ WT,
                     const float* __restrict__ b_rnn, const float* __restrict__ Wd,
                     const float* __restrict__ bd, float* __restrict__ out) {
    extern __shared__ char smem[];
    unsigned short* afrag = (unsigned short*)smem;   // 16 KB: h_t in A-frag order
    char* wlds = smem + 16384;                       // 4 waves * 34 frags * 1 KB

    const int tid  = threadIdx.x;
    const int lane = tid & 63;
    const int w    = tid >> 6;       // wave 0..3
    const int c    = lane & 15;
    const int quad = lane >> 4;
    const int r0   = blockIdx.x * ROWS;

    // ---- AGPR tier: kc 2..9 ----
    floatx4 agf[64];
#pragma unroll
    for (int kc = 2; kc < 10; ++kc)
#pragma unroll
        for (int p = 0; p < 8; ++p)
            agf[(kc - 2) * 8 + p] = *(const floatx4*)(
                WT + (((size_t)(w * 8 + p) * 18 + kc) * 64 + lane) * 8);
    // ---- VGPR tier: kc10 -> vgf[p], kc11 -> vgf[8+p], kc12 p<4 -> vgf[16+p] ----
    floatx4 vgf[20];
#pragma unroll
    for (int p = 0; p < 8; ++p)
        vgf[p] = *(const floatx4*)(WT + (((size_t)(w * 8 + p) * 18 + 10) * 64 + lane) * 8);
#pragma unroll
    for (int p = 0; p < 8; ++p)
        vgf[8 + p] = *(const floatx4*)(WT + (((size_t)(w * 8 + p) * 18 + 11) * 64 + lane) * 8);
#pragma unroll
    for (int p = 0; p < 4; ++p)
        vgf[16 + p] = *(const floatx4*)(WT + (((size_t)(w * 8 + p) * 18 + 12) * 64 + lane) * 8);
#pragma unroll
    for (int i = 0; i < 64; ++i) KEEPA(agf[i]);
#pragma unroll
    for (int i = 0; i < 20; ++i) KEEPV(vgf[i]);

    // ---- LDS tier: l<4:(kc12,p=l+4); l<28:(kc 13+(l-4)/8, p=(l-4)&7); else (kc16, p=l-28)
#pragma unroll
    for (int l = 0; l < N_LDSF; ++l) {
        int kc, p;
        if (l < 4)       { kc = 12;               p = l + 4; }
        else if (l < 28) { kc = 13 + ((l - 4) >> 3); p = (l - 4) & 7; }
        else             { kc = 16;               p = l - 28; }
        *(uint4*)(wlds + ((w * N_LDSF + l) << 10) + lane * 16) =
            *(const uint4*)(WT + (((size_t)(w * 8 + p) * 18 + kc) * 64 + lane) * 8);
    }

    // stream byte bases (kc=0 of ng=w*8+p); frag(kc,p) at svb[p] + (kc<<10)
    unsigned svb[8];
#pragma unroll
    for (int p = 0; p < 8; ++p)
        svb[p] = ((unsigned)((w * 8 + p) * 18) << 10) + lane * 16;

    float bias[8];
#pragma unroll
    for (int p = 0; p < 8; ++p) bias[p] = b_rnn[(w * 8 + p) * 16 + c];

    // h-write byte offsets (A-frag position of own cols, r=0; +16B per r)
    int hoff[8];
#pragma unroll
    for (int p = 0; p < 8; ++p) {
        const int col = (w * 8 + p) * 16 + c;
        hoff[p] = (((col >> 5) * 64 + ((col >> 3) & 3) * 16 + quad * 4) * 8 + (col & 7)) * 2;
    }

    for (int i = tid; i < 1024; i += THREADS)
        ((uint4*)afrag)[i] = make_uint4(0, 0, 0, 0);
    __syncthreads();

    const char* aLane = (const char*)afrag + lane * 16;
    const char* wLane = wlds + (w * N_LDSF) * 1024 + lane * 16;
    const char* wtB   = (const char*)WT;
    const float* xrow = x + ((size_t)(r0 + c) * T_STEPS) * D_IN + quad * 8;

#pragma unroll 1
    for (int t = 0; t < T_STEPS; ++t) {
        // x_t loads (consumed at tail)
        const float* xp = xrow + (size_t)t * D_IN;
        floatx4 xa = *(const floatx4*)(xp);
        floatx4 xb = *(const floatx4*)(xp + 4);
        floatx4 xc = *(const floatx4*)(xp + 32);
        floatx4 xd = *(const floatx4*)(xp + 36);

        // stream group 1: kc16 p6,7 + kc17 p0..7 (consumed at kc16/17)
        floatx4 s1[10];
#pragma unroll
        for (int i = 0; i < 10; ++i) {
            const int kc = (i < 2) ? 16 : 17;
            const int p  = (i < 2) ? (6 + i) : (i - 2);
            s1[i] = *(const floatx4*)(wtB + svb[p] + (kc << 10));
        }

        // A-frags first half (kc 2..9)
        bf16x8 aH1[8];
#pragma unroll
        for (int i = 0; i < 8; ++i)
            aH1[i] = *(const bf16x8*)(aLane + i * 1024);

        floatx4 acc[8];
#pragma unroll
        for (int p = 0; p < 8; ++p)
            acc[p] = (floatx4){bias[p], bias[p], bias[p], bias[p]};

        // kc 2..9 (AGPR weights)
#pragma unroll
        for (int i = 0; i < 8; ++i)
#pragma unroll
            for (int p = 0; p < 8; ++p)
                acc[p] = __builtin_amdgcn_mfma_f32_16x16x32_bf16(
                    aH1[i], BC8(agf[i * 8 + p]), acc[p], 0, 0, 0);

        // stream group 2: kc0
        floatx4 s2[8];
#pragma unroll
        for (int p = 0; p < 8; ++p)
            s2[p] = *(const floatx4*)(wtB + svb[p]);

        // A-frags second half (kc 10..17)
        bf16x8 aH2[8];
#pragma unroll
        for (int i = 0; i < 8; ++i)
            aH2[i] = *(const bf16x8*)(aLane + (8 + i) * 1024);

        // stream group 3: kc1
        floatx4 s3[8];
#pragma unroll
        for (int p = 0; p < 8; ++p)
            s3[p] = *(const floatx4*)(wtB + svb[p] + 1024);

        // kc10, kc11 (VGPR weights)
#pragma unroll
        for (int p = 0; p < 8; ++p)
            acc[p] = __builtin_amdgcn_mfma_f32_16x16x32_bf16(aH2[0], BC8(vgf[p]), acc[p], 0, 0, 0);
#pragma unroll
        for (int p = 0; p < 8; ++p)
            acc[p] = __builtin_amdgcn_mfma_f32_16x16x32_bf16(aH2[1], BC8(vgf[8 + p]), acc[p], 0, 0, 0);
        // kc12: p<4 VGPR, p>=4 LDS (l = p-4)
#pragma unroll
        for (int p = 0; p < 4; ++p)
            acc[p] = __builtin_amdgcn_mfma_f32_16x16x32_bf16(aH2[2], BC8(vgf[16 + p]), acc[p], 0, 0, 0);
#pragma unroll
        for (int p = 4; p < 8; ++p)
            acc[p] = __builtin_amdgcn_mfma_f32_16x16x32_bf16(
                aH2[2], *(const bf16x8*)(wLane + (p - 4) * 1024), acc[p], 0, 0, 0);
        // kc13..15: LDS (l = 4 + (kc-13)*8 + p)
#pragma unroll
        for (int kc = 13; kc < 16; ++kc)
#pragma unroll
            for (int p = 0; p < 8; ++p)
                acc[p] = __builtin_amdgcn_mfma_f32_16x16x32_bf16(
                    aH2[kc - 10], *(const bf16x8*)(wLane + (4 + (kc - 13) * 8 + p) * 1024),
                    acc[p], 0, 0, 0);
        // kc16: p<6 LDS (l = 28+p), p>=6 stream s1[p-6]
#pragma unroll
        for (int p = 0; p < 6; ++p)
            acc[p] = __builtin_amdgcn_mfma_f32_16x16x32_bf16(
                aH2[6], *(const bf16x8*)(wLane + (28 + p) * 1024), acc[p], 0, 0, 0);
#pragma unroll
        for (int p = 6; p < 8; ++p)
            acc[p] = __builtin_amdgcn_mfma_f32_16x16x32_bf16(aH2[6], BC8(s1[p - 6]), acc[p], 0, 0, 0);
        // kc17: stream s1[2+p]
#pragma unroll
        for (int p = 0; p < 8; ++p)
            acc[p] = __builtin_amdgcn_mfma_f32_16x16x32_bf16(aH2[7], BC8(s1[2 + p]), acc[p], 0, 0, 0);

        // x-part (kc 0,1): A from registers, B streamed
        {
            bf16x8 a0 = cvt8(xa, xb);
            bf16x8 a1 = cvt8(xc, xd);
#pragma unroll
            for (int p = 0; p < 8; ++p)
                acc[p] = __builtin_amdgcn_mfma_f32_16x16x32_bf16(a0, BC8(s2[p]), acc[p], 0, 0, 0);
#pragma unroll
            for (int p = 0; p < 8; ++p)
                acc[p] = __builtin_amdgcn_mfma_f32_16x16x32_bf16(a1, BC8(s3[p]), acc[p], 0, 0, 0);
        }

        __syncthreads();   // all waves done reading h_{t-1}

        // epilogue: relu + pack h_t
#pragma unroll
        for (int p = 0; p < 8; ++p) {
#pragma unroll
            for (int r = 0; r < 4; ++r) {
                float v = acc[p][r];
                v = v > 0.f ? v : 0.f;
                *(unsigned short*)((char*)afrag + hoff[p] + r * 16) =
                    __builtin_bit_cast(unsigned short, (__bf16)v);
            }
        }
        __syncthreads();
    }

    // ---- output head: out[b] = relu(h_511[b,:] . Wd + bd) ----
    {
        const int m  = tid >> 4;     // batch row
        const int cs = tid & 15;     // 32-col chunk
        float sum = 0.f;
#pragma unroll
        for (int q2 = 0; q2 < 4; ++q2) {
            const bf16x8 hv = *(const bf16x8*)(&afrag[cs * 512 + (q2 * 16 + m) * 8]);
#pragma unroll
            for (int j = 0; j < 8; ++j)
                sum += (float)hv[j] * Wd[cs * 32 + q2 * 8 + j];
        }
#pragma unroll
        for (int off = 1; off < 16; off <<= 1) sum += __shfl_xor(sum, off, 64);
        if (cs == 0) {
            float v = sum + bd[0];
            out[r0 + m] = v > 0.f ? v : 0.f;
        }
    }
}

extern "C" void kernel_launch(void* const* d_in, const int* in_sizes, int n_in,
                              void* d_out, int out_size, void* d_ws, size_t ws_size,
                              hipStream_t stream) {
    const float* x    = (const float*)d_in[0];
    const float* Wx   = (const float*)d_in[1];
    const float* Wh   = (const float*)d_in[2];
    const float* brnn = (const float*)d_in[3];
    const float* Wd   = (const float*)d_in[4];
    const float* bd   = (const float*)d_in[5];
    float* out = (float*)d_out;

    unsigned short* WT = (unsigned short*)d_ws;   // 589824 B

    prep_kernel<<<(512 * 576 + 255) / 256, 256, 0, stream>>>(Wx, Wh, WT);

    const int smem_bytes = 16384 + 4 * N_LDSF * 1024;   // 155648
    hipFuncSetAttribute((const void*)rnn_scan_kernel,
                        hipFuncAttributeMaxDynamicSharedMemorySize, smem_bytes);
    rnn_scan_kernel<<<32, THREADS, smem_bytes, stream>>>(x, WT, brnn, Wd, bd, out);
}